// Round 1
// baseline (382.615 us; speedup 1.0000x reference)
//
#include <hip/hip_runtime.h>
#include <math.h>

#define DFEAT 4096
#define NQ 6
#define ROWS_PER_WAVE 4
#define WAVES_PER_BLOCK 4
#define ROWS_PER_BLOCK (ROWS_PER_WAVE * WAVES_PER_BLOCK)

// Fused: h = x@W1 + b1; a = h/||h||; 15 RBS (Givens) rotations; z = 1-2a^2
// (NaN->0); out = sigmoid(z@W2 + b2).
// One wave handles 4 rows: lane i streams float4 of x (coalesced), W1 chunk
// (24 contiguous floats per lane) loaded once and reused across the 4 rows.
__global__ __launch_bounds__(256, 4)
void hybrid_fused_kernel(const float* __restrict__ x,
                         const float* __restrict__ W1,
                         const float* __restrict__ b1,
                         const float* __restrict__ qw,
                         const float* __restrict__ W2,
                         const float* __restrict__ b2,
                         float* __restrict__ out, int B)
{
    const int lane = threadIdx.x & 63;
    const int wave_in_block = threadIdx.x >> 6;
    const int row0 = (blockIdx.x * WAVES_PER_BLOCK + wave_in_block) * ROWS_PER_WAVE;
    if (row0 >= B) return;

    // Row base pointers (clamped for safety; B=16384 is divisible by 4).
    const float* xp[ROWS_PER_WAVE];
#pragma unroll
    for (int r = 0; r < ROWS_PER_WAVE; ++r) {
        int rr = row0 + r; if (rr > B - 1) rr = B - 1;
        xp[r] = x + (size_t)rr * DFEAT;
    }

    float acc[ROWS_PER_WAVE][NQ];
#pragma unroll
    for (int r = 0; r < ROWS_PER_WAVE; ++r)
#pragma unroll
        for (int j = 0; j < NQ; ++j) acc[r][j] = 0.0f;

    // Main streaming loop: 16 iterations, 256 d's per wave per iteration.
    for (int it = 0; it < DFEAT / 256; ++it) {
        const int d = it * 256 + lane * 4;

        // W1 rows d..d+3: 24 contiguous floats, 16B-aligned (d%4==0 -> 96B).
        float w[24];
        const float4* wp = reinterpret_cast<const float4*>(W1 + (size_t)d * NQ);
#pragma unroll
        for (int m = 0; m < 6; ++m)
            reinterpret_cast<float4*>(w)[m] = wp[m];

#pragma unroll
        for (int r = 0; r < ROWS_PER_WAVE; ++r) {
            const float4 xv = *reinterpret_cast<const float4*>(xp[r] + d);
            const float xs[4] = {xv.x, xv.y, xv.z, xv.w};
#pragma unroll
            for (int k = 0; k < 4; ++k)
#pragma unroll
                for (int j = 0; j < NQ; ++j)
                    acc[r][j] = fmaf(xs[k], w[k * NQ + j], acc[r][j]);
        }
    }

    // Wave-wide butterfly reduction: every lane ends with the full sums.
#pragma unroll
    for (int r = 0; r < ROWS_PER_WAVE; ++r)
#pragma unroll
        for (int j = 0; j < NQ; ++j) {
            float v = acc[r][j];
#pragma unroll
            for (int off = 32; off >= 1; off >>= 1)
                v += __shfl_xor(v, off, 64);
            acc[r][j] = v;
        }

    // Tail: lanes 0..3 each finish one row (tiny: ~60 flops + 15 sincos).
    if (lane < ROWS_PER_WAVE) {
        float h[NQ];
#pragma unroll
        for (int j = 0; j < NQ; ++j) {
            float v = acc[0][j];
            v = (lane == 1) ? acc[1][j] : v;
            v = (lane == 2) ? acc[2][j] : v;
            v = (lane == 3) ? acc[3][j] : v;
            h[j] = v + b1[j];
        }
        float n2 = 0.0f;
#pragma unroll
        for (int j = 0; j < NQ; ++j) n2 = fmaf(h[j], h[j], n2);
        const float inv = rsqrtf(n2);
        float a[NQ];
#pragma unroll
        for (int j = 0; j < NQ; ++j) a[j] = h[j] * inv;

        // pyramid_top_wires(6) = [4,3,2,4,1,3,0,2,4,1,3,2,4,3,4]
        const int topw[15] = {4,3,2,4,1,3,0,2,4,1,3,2,4,3,4};
#pragma unroll
        for (int k = 0; k < 15; ++k) {
            const int q = topw[k];          // constant after unroll
            const float c = cosf(qw[k]);
            const float s = sinf(qw[k]);
            const float aq  = fmaf(c, a[q],     s * a[q + 1]);
            const float aq1 = fmaf(c, a[q + 1], -s * a[q]);
            a[q] = aq;
            a[q + 1] = aq1;
        }

        float zac = b2[0];
#pragma unroll
        for (int j = 0; j < NQ; ++j) {
            float z = 1.0f - 2.0f * a[j] * a[j];
            z = isnan(z) ? 0.0f : z;        // NaN guard from reference
            zac = fmaf(z, W2[j], zac);
        }
        const float o = 1.0f / (1.0f + expf(-zac));
        const int row = row0 + lane;
        if (row < B) out[row] = o;
    }
}

extern "C" void kernel_launch(void* const* d_in, const int* in_sizes, int n_in,
                              void* d_out, int out_size, void* d_ws, size_t ws_size,
                              hipStream_t stream) {
    const float* x  = (const float*)d_in[0];
    const float* W1 = (const float*)d_in[1];
    const float* b1 = (const float*)d_in[2];
    const float* qw = (const float*)d_in[3];
    const float* W2 = (const float*)d_in[4];
    const float* b2 = (const float*)d_in[5];
    float* out = (float*)d_out;

    const int B = in_sizes[0] / DFEAT;                      // 16384
    const int blocks = (B + ROWS_PER_BLOCK - 1) / ROWS_PER_BLOCK;  // 1024
    hybrid_fused_kernel<<<blocks, 256, 0, stream>>>(x, W1, b1, qw, W2, b2, out, B);
}